// Round 12
// baseline (737.737 us; speedup 1.0000x reference)
//
#include <hip/hip_runtime.h>

#define BB 64
#define LL 512
#define DD 1024
#define CC 131
#define CP 132
#define START_I 129
#define STOP_I 130
#define NEGV -10000.0f

// Raw workgroup barrier: makes LDS writes visible without draining vmcnt
// (so global stores/prefetches stay in flight across steps).
__device__ __forceinline__ void lds_barrier() {
    asm volatile("s_waitcnt lgkmcnt(0)" ::: "memory");
    __builtin_amdgcn_s_barrier();
    __builtin_amdgcn_sched_barrier(0);
}

// lane-broadcast read of this wave's register (const lane index)
#define RL(src, i) __int_as_float(__builtin_amdgcn_readlane(__float_as_int(src), (i)))

// ---------------- Kernel 1: feats[m][c] = dot(x[m,:], W[c,:]) + b[c] (unchanged) ------
#define GM 64
#define GK 32
#define LSTR 36

__global__ __launch_bounds__(256, 2) void gemm_feats(
    const float* __restrict__ x, const float* __restrict__ W,
    const float* __restrict__ bias, float* __restrict__ feats)
{
    __shared__ float xs[GM * LSTR];   // [m][k] 64x36
    __shared__ float ws[CP * LSTR];   // [j][k] 132x36

    const int tid = threadIdx.x;
    const int m0 = blockIdx.x * GM;
    const int tm = tid & 15;          // rows tm + 16r (r<4)
    const int tj = (tid >> 4) & 15;   // cols tj + 16c (c<8)
    const bool tail = (tj < 3);
    const int tjt = (tj < 3) ? tj : 2;

    float acc[4][8];
    float acct[4];
#pragma unroll
    for (int r = 0; r < 4; ++r) {
        acct[r] = 0.f;
#pragma unroll
        for (int c = 0; c < 8; ++c) acc[r][c] = 0.f;
    }

    for (int kc = 0; kc < DD / GK; ++kc) {
        const int k0 = kc * GK;
        if (kc) __syncthreads();
#pragma unroll
        for (int q = 0; q < 2; ++q) {
            int lin = tid + q * 256;
            int m = lin >> 3, c4 = lin & 7;
            float4 v = *(const float4*)&x[(size_t)(m0 + m) * DD + k0 + c4 * 4];
            *(float4*)&xs[m * LSTR + c4 * 4] = v;
        }
#pragma unroll
        for (int q = 0; q < 5; ++q) {
            int lin = tid + q * 256;
            if (lin < CC * 8) {
                int r = lin >> 3, c4 = lin & 7;
                float4 v = *(const float4*)&W[(size_t)r * DD + k0 + c4 * 4];
                *(float4*)&ws[r * LSTR + c4 * 4] = v;
            }
        }
        __syncthreads();

#pragma unroll
        for (int k4 = 0; k4 < 8; ++k4) {
            float4 xr[4], wr[8], wt;
#pragma unroll
            for (int r = 0; r < 4; ++r)
                xr[r] = *(const float4*)&xs[(tm + 16 * r) * LSTR + k4 * 4];
#pragma unroll
            for (int c = 0; c < 8; ++c)
                wr[c] = *(const float4*)&ws[(tj + 16 * c) * LSTR + k4 * 4];
            wt = *(const float4*)&ws[(128 + tjt) * LSTR + k4 * 4];
#pragma unroll
            for (int r = 0; r < 4; ++r) {
#pragma unroll
                for (int c = 0; c < 8; ++c) {
                    acc[r][c] = fmaf(xr[r].x, wr[c].x, acc[r][c]);
                    acc[r][c] = fmaf(xr[r].y, wr[c].y, acc[r][c]);
                    acc[r][c] = fmaf(xr[r].z, wr[c].z, acc[r][c]);
                    acc[r][c] = fmaf(xr[r].w, wr[c].w, acc[r][c]);
                }
                acct[r] = fmaf(xr[r].x, wt.x, acct[r]);
                acct[r] = fmaf(xr[r].y, wt.y, acct[r]);
                acct[r] = fmaf(xr[r].z, wt.z, acct[r]);
                acct[r] = fmaf(xr[r].w, wt.w, acct[r]);
            }
        }
    }

#pragma unroll
    for (int c = 0; c < 8; ++c) {
        int j = tj + 16 * c;
        float bv = bias[j];
#pragma unroll
        for (int r = 0; r < 4; ++r)
            feats[(size_t)(m0 + tm + 16 * r) * CP + j] = acc[r][c] + bv;
    }
    if (tail) {
        int j = 128 + tj;
        float bv = bias[j];
#pragma unroll
        for (int r = 0; r < 4; ++r)
            feats[(size_t)(m0 + tm + 16 * r) * CP + j] = acct[r] + bv;
    }
}

// ---------------- Kernel 2: Viterbi forward v12 ---------------------------------------
// 64 blocks x 512 threads (8 waves). Wave = (jg = w>>2: columns jg*64+lane,
// sub = w&3: i-slice [sub*33, sub*33+33)). Per step:
//   COMBINE (lanes 0..32): s_t[i] for i in own slice = blend(max of 4 pbuf partials + f)
//     -- 4 stride-1 ds_read_b32, state lives in register sa. No sbuf exists.
//   SCAN: partial for 64 columns over slice via 33 readlane broadcasts from sa
//     (VALU pipe only, ZERO LDS reads; T slice = 33 scalars, resident per r11's
//     VGPR=48 evidence at 40 floats) -> 1 pbuf[wb] write.
//   Tail cols 128..130: jg=0 waves reduce 3 candidate rows via 6 shfl_xor.
// ONE lgkm barrier per step (pbuf double-buffered; combine reads rb, scan writes wb).
// All candidate values are identical single adds; fmax exact in any order ->
// hist bit-identical to reference recurrence.
__global__ __launch_bounds__(512, 1) void viterbi_fwd(
    const float* __restrict__ feats, const float* __restrict__ mask,
    const float* __restrict__ trans, float* __restrict__ hist)
{
    const int b = blockIdx.x;
    const int tid = threadIdx.x;
    const int w = tid >> 6, lane = tid & 63;
    const int jg = w >> 2;                 // column group
    const int sub = w & 3;                 // i-slice
    const int j = jg * 64 + lane;          // scan column (0..127)
    const int i0 = sub * 33;               // slice base
    const int ic = i0 + lane;              // combine column (lanes 0..32)
    const bool cl = (lane < 33) && (ic < CC);   // combine lane (sub3 lane32 = pad 131)
    const bool hw = (jg == 0) && cl;       // hist writer

    __shared__ float pbuf[2][4][136];      // [buf][sub][col]

    // ---- T slice: 33 scalars (small -> resident), col j, i in [i0, i0+33)
    float Tk[33];
    {
        const float* tr = trans + (size_t)j * CC + i0;
#pragma unroll
        for (int k = 0; k < 33; ++k)
            Tk[k] = (i0 + k < CC) ? tr[k] : NEGV;
    }
    // ---- tail rows (jg=0 waves): T[128..130][ic]
    float tA = NEGV, tB = NEGV, tC = NEGV;
    if (jg == 0 && cl) {
        tA = trans[(size_t)128 * CC + ic];
        tB = trans[(size_t)129 * CC + ic];
        tC = trans[(size_t)130 * CC + ic];
    }

    const float* fb = feats + (size_t)b * LL * CP;
    const float* mb = mask + (size_t)b * LL;
    float* hb = hist + (size_t)b * LL * CP;

    // ---- state register: sa = s[ic] (lanes 0..32; others stay NEGV forever)
    float sa = (cl && ic == START_I) ? 0.f : NEGV;

    // scan + tail-partials into pbuf[WB]
#define SCAN(WB)                                                                  \
    {                                                                             \
        float a0 = -3.0e38f, a1 = -3.0e38f;                                       \
        _Pragma("unroll")                                                         \
        for (int q = 0; q < 8; ++q) {                                             \
            a0 = fmaxf(fmaxf(RL(sa, 4*q+0) + Tk[4*q+0],                           \
                             RL(sa, 4*q+1) + Tk[4*q+1]), a0);                     \
            a1 = fmaxf(fmaxf(RL(sa, 4*q+2) + Tk[4*q+2],                           \
                             RL(sa, 4*q+3) + Tk[4*q+3]), a1);                     \
        }                                                                         \
        a0 = fmaxf(a0, RL(sa, 32) + Tk[32]);                                      \
        pbuf[WB][sub][j] = fmaxf(a0, a1);                                         \
        if (jg == 0) {                                                            \
            float cA = cl ? (sa + tA) : -3.0e38f;                                 \
            float cB = cl ? (sa + tB) : -3.0e38f;                                 \
            float cC = cl ? (sa + tC) : -3.0e38f;                                 \
            _Pragma("unroll")                                                     \
            for (int off = 1; off < 64; off <<= 1) {                              \
                cA = fmaxf(cA, __shfl_xor(cA, off, 64));                          \
                cB = fmaxf(cB, __shfl_xor(cB, off, 64));                          \
                cC = fmaxf(cC, __shfl_xor(cC, off, 64));                          \
            }                                                                     \
            if (lane == 0) {                                                      \
                pbuf[WB][sub][128] = cA;                                          \
                pbuf[WB][sub][129] = cB;                                          \
                pbuf[WB][sub][130] = cC;                                          \
            }                                                                     \
        }                                                                         \
    }

    // prologue: scan s_init -> pbuf[0]
    SCAN(0)
    lds_barrier();

    // ---- rings (combine lanes)
    float fv0 = 0.f, fv1 = 0.f;
    if (cl) { fv0 = fb[ic]; fv1 = fb[CP + ic]; }
    float mv0 = mb[0], mv1 = mb[1];
    const float* fb_t = fb + 2 * CP + ic;
    const float* mb_t = mb + 2;
    float* hb_t = hb + ic;

    for (int t = 0; t < LL; ++t) {
        const int rb = t & 1, wb = rb ^ 1;
        float fv2 = 0.f, mv2 = 1.f;
        if (t + 2 < LL) { if (cl) fv2 = *fb_t; mv2 = *mb_t; }
        fb_t += CP; ++mb_t;

        // ---- combine: s_t for own slice (4 stride-1 b32 reads, conflict-free)
        if (cl) {
            float p01 = fmaxf(pbuf[rb][0][ic], pbuf[rb][1][ic]);
            float p23 = fmaxf(pbuf[rb][2][ic], pbuf[rb][3][ic]);
            float ns = (mv0 != 0.f) ? (fmaxf(p01, p23) + fv0) : sa;
            sa = ns;
            if (hw) *hb_t = ns;            // global store; lds_barrier never drains it
        }
        hb_t += CP;

        // ---- scan s_t -> pbuf[wb] (skip after last step)
        if (t < LL - 1) SCAN(wb)

        lds_barrier();
        fv0 = fv1; fv1 = fv2; mv0 = mv1; mv1 = mv2;
    }
#undef SCAN
}

// ---------------- Kernel 3: backpointer matrix (unchanged) ----------------
__global__ __launch_bounds__(256, 4) void bp_kernel(
    const float* __restrict__ hist, const float* __restrict__ trans,
    unsigned char* __restrict__ bp)
{
    const int b  = blockIdx.x / 5;
    const int jc = blockIdx.x % 5;
    const int tc = blockIdx.y;
    const int tid = threadIdx.x;
    const int j0 = jc * 32;

    __shared__ float Ts[32][136];
    __shared__ float hs[8][132];

    for (int q = 0; q < 17; ++q) {
        int lin = tid + q * 256;
        if (lin < 32 * CC) {
            int r = lin / CC, i = lin - r * CC;
            if (j0 + r < CC) Ts[r][i] = trans[(size_t)(j0 + r) * CC + i];
        }
    }
    {
        const float4* src = (const float4*)(hist + ((size_t)b * LL + tc * 8) * CP);
#pragma unroll
        for (int q = 0; q < 2; ++q) {
            int lin = tid + q * 256;
            if (lin < (8 * CP) / 4) ((float4*)hs)[lin] = src[lin];
        }
    }
    __syncthreads();

    const int jl = tid & 31;
    const int tt = tid >> 5;
    const int j = j0 + jl;
    const int t = tc * 8 + tt + 1;
    if (j >= CC || t >= LL) return;

    float best; int idx;
    {
        float4 tv = *(const float4*)&Ts[jl][128];
        float4 hv = *(const float4*)&hs[tt][128];
        best = hv.z + tv.z; idx = 130;
        float v;
        v = hv.y + tv.y; if (v >= best) { best = v; idx = 129; }
        v = hv.x + tv.x; if (v >= best) { best = v; idx = 128; }
    }
#pragma unroll
    for (int i4 = 31; i4 >= 0; --i4) {
        float4 tv = *(const float4*)&Ts[jl][i4 * 4];
        float4 hv = *(const float4*)&hs[tt][i4 * 4];
        float v;
        v = hv.w + tv.w; if (v >= best) { best = v; idx = i4 * 4 + 3; }
        v = hv.z + tv.z; if (v >= best) { best = v; idx = i4 * 4 + 2; }
        v = hv.y + tv.y; if (v >= best) { best = v; idx = i4 * 4 + 1; }
        v = hv.x + tv.x; if (v >= best) { best = v; idx = i4 * 4 + 0; }
    }
    bp[((size_t)b * LL + t) * CP + j] = (unsigned char)idx;
}

// ---------------- Kernel 4: final argmax + LDS-streamed u8 backtrack (unchanged) ------
__global__ __launch_bounds__(64, 1) void viterbi_btr(
    const float* __restrict__ hist, const float* __restrict__ trans,
    const unsigned char* __restrict__ bp,
    float* __restrict__ out_score, float* __restrict__ out_path)
{
    const int b = blockIdx.x;
    const int lane = threadIdx.x;
    const float* hb = hist + ((size_t)b * LL + (LL - 1)) * CP;
    const float* ts = trans + (size_t)STOP_I * CC;

    float v0 = hb[lane] + ts[lane];
    float v1 = hb[lane + 64] + ts[lane + 64];
    float v2 = (lane < 3) ? (hb[lane + 128] + ts[lane + 128]) : -3.0e38f;

    float best = v0; int idx = lane;
    if (v1 > best) { best = v1; idx = lane + 64; }
    if (v2 > best) { best = v2; idx = lane + 128; }
#pragma unroll
    for (int off = 32; off >= 1; off >>= 1) {
        float ob = __shfl_xor(best, off, 64);
        int   oi = __shfl_xor(idx, off, 64);
        if (ob > best || (ob == best && oi < idx)) { best = ob; idx = oi; }
    }

    float* op = out_path + (size_t)b * LL;
    if (lane == 0) {
        out_score[b] = best;
        op[LL - 1] = (float)idx;
    }
    int tag = idx;

    __shared__ unsigned char buf[2][1088];
    const unsigned char* bpb = bp + (size_t)b * LL * CP;

    {
        const unsigned int* src = (const unsigned int*)(bpb + (size_t)504 * CP);
        unsigned int* dst = (unsigned int*)buf[1];
#pragma unroll
        for (int q = 0; q < 5; ++q) {
            int lin = lane + q * 64;
            if (lin < 264) dst[lin] = src[lin];
        }
    }
    lds_barrier();

    int cur = 1;
    for (int k = 63; k >= 0; --k) {
        unsigned int r0 = 0, r1 = 0, r2 = 0, r3 = 0, r4 = 0;
        if (k > 0) {
            const unsigned int* src = (const unsigned int*)(bpb + (size_t)(k - 1) * 8 * CP);
            r0 = src[lane];
            r1 = src[lane + 64];
            r2 = src[lane + 128];
            r3 = src[lane + 192];
            if (lane < 8) r4 = src[lane + 256];
        }
        const unsigned char* cb = buf[cur];
#pragma unroll
        for (int s = 7; s >= 0; --s) {
            int t = k * 8 + s;
            if (t >= 1) {
                tag = cb[s * CP + tag];
                if (lane == 0) op[t - 1] = (float)tag;
            }
        }
        if (k > 0) {
            unsigned int* dst = (unsigned int*)buf[cur ^ 1];
            dst[lane] = r0;
            dst[lane + 64] = r1;
            dst[lane + 128] = r2;
            dst[lane + 192] = r3;
            if (lane < 8) dst[lane + 256] = r4;
            lds_barrier();
        }
        cur ^= 1;
    }
}

extern "C" void kernel_launch(void* const* d_in, const int* in_sizes, int n_in,
                              void* d_out, int out_size, void* d_ws, size_t ws_size,
                              hipStream_t stream)
{
    const float* x     = (const float*)d_in[0];
    const float* mask  = (const float*)d_in[1];
    const float* W     = (const float*)d_in[2];
    const float* bias  = (const float*)d_in[3];
    const float* trans = (const float*)d_in[4];

    float* feats = (float*)d_ws;
    float* hist  = feats + (size_t)BB * LL * CP;
    unsigned char* bp = (unsigned char*)(hist + (size_t)BB * LL * CP);
    float* out_score = (float*)d_out;
    float* out_path  = out_score + BB;

    hipLaunchKernelGGL(gemm_feats, dim3((BB * LL) / GM), dim3(256), 0, stream, x, W, bias, feats);
    hipLaunchKernelGGL(viterbi_fwd, dim3(BB), dim3(512), 0, stream, feats, mask, trans, hist);
    hipLaunchKernelGGL(bp_kernel, dim3(BB * 5, 64), dim3(256), 0, stream, hist, trans, bp);
    hipLaunchKernelGGL(viterbi_btr, dim3(BB), dim3(64), 0, stream, hist, trans, bp, out_score, out_path);
}

// Round 13
// 595.117 us; speedup vs baseline: 1.2397x; 1.2397x over previous
//
#include <hip/hip_runtime.h>

#define BB 64
#define LL 512
#define DD 1024
#define CC 131
#define CP 132
#define START_I 129
#define STOP_I 130
#define NEGV -10000.0f

// Raw workgroup barrier: makes LDS writes visible without draining vmcnt
// (so global stores/prefetches stay in flight across steps).
__device__ __forceinline__ void lds_barrier() {
    asm volatile("s_waitcnt lgkmcnt(0)" ::: "memory");
    __builtin_amdgcn_s_barrier();
    __builtin_amdgcn_sched_barrier(0);
}

// ---------------- Kernel 1: feats[m][c] = dot(x[m,:], W[c,:]) + b[c] (unchanged) ------
#define GM 64
#define GK 32
#define LSTR 36

__global__ __launch_bounds__(256, 2) void gemm_feats(
    const float* __restrict__ x, const float* __restrict__ W,
    const float* __restrict__ bias, float* __restrict__ feats)
{
    __shared__ float xs[GM * LSTR];   // [m][k] 64x36
    __shared__ float ws[CP * LSTR];   // [j][k] 132x36

    const int tid = threadIdx.x;
    const int m0 = blockIdx.x * GM;
    const int tm = tid & 15;          // rows tm + 16r (r<4)
    const int tj = (tid >> 4) & 15;   // cols tj + 16c (c<8)
    const bool tail = (tj < 3);
    const int tjt = (tj < 3) ? tj : 2;

    float acc[4][8];
    float acct[4];
#pragma unroll
    for (int r = 0; r < 4; ++r) {
        acct[r] = 0.f;
#pragma unroll
        for (int c = 0; c < 8; ++c) acc[r][c] = 0.f;
    }

    for (int kc = 0; kc < DD / GK; ++kc) {
        const int k0 = kc * GK;
        if (kc) __syncthreads();
#pragma unroll
        for (int q = 0; q < 2; ++q) {
            int lin = tid + q * 256;
            int m = lin >> 3, c4 = lin & 7;
            float4 v = *(const float4*)&x[(size_t)(m0 + m) * DD + k0 + c4 * 4];
            *(float4*)&xs[m * LSTR + c4 * 4] = v;
        }
#pragma unroll
        for (int q = 0; q < 5; ++q) {
            int lin = tid + q * 256;
            if (lin < CC * 8) {
                int r = lin >> 3, c4 = lin & 7;
                float4 v = *(const float4*)&W[(size_t)r * DD + k0 + c4 * 4];
                *(float4*)&ws[r * LSTR + c4 * 4] = v;
            }
        }
        __syncthreads();

#pragma unroll
        for (int k4 = 0; k4 < 8; ++k4) {
            float4 xr[4], wr[8], wt;
#pragma unroll
            for (int r = 0; r < 4; ++r)
                xr[r] = *(const float4*)&xs[(tm + 16 * r) * LSTR + k4 * 4];
#pragma unroll
            for (int c = 0; c < 8; ++c)
                wr[c] = *(const float4*)&ws[(tj + 16 * c) * LSTR + k4 * 4];
            wt = *(const float4*)&ws[(128 + tjt) * LSTR + k4 * 4];
#pragma unroll
            for (int r = 0; r < 4; ++r) {
#pragma unroll
                for (int c = 0; c < 8; ++c) {
                    acc[r][c] = fmaf(xr[r].x, wr[c].x, acc[r][c]);
                    acc[r][c] = fmaf(xr[r].y, wr[c].y, acc[r][c]);
                    acc[r][c] = fmaf(xr[r].z, wr[c].z, acc[r][c]);
                    acc[r][c] = fmaf(xr[r].w, wr[c].w, acc[r][c]);
                }
                acct[r] = fmaf(xr[r].x, wt.x, acct[r]);
                acct[r] = fmaf(xr[r].y, wt.y, acct[r]);
                acct[r] = fmaf(xr[r].z, wt.z, acct[r]);
                acct[r] = fmaf(xr[r].w, wt.w, acct[r]);
            }
        }
    }

#pragma unroll
    for (int c = 0; c < 8; ++c) {
        int j = tj + 16 * c;
        float bv = bias[j];
#pragma unroll
        for (int r = 0; r < 4; ++r)
            feats[(size_t)(m0 + tm + 16 * r) * CP + j] = acc[r][c] + bv;
    }
    if (tail) {
        int j = 128 + tj;
        float bv = bias[j];
#pragma unroll
        for (int r = 0; r < 4; ++r)
            feats[(size_t)(m0 + tm + 16 * r) * CP + j] = acct[r] + bv;
    }
}

// ---------------- Kernel 2: Viterbi forward v13 ---------------------------------------
// 64 blocks x 512 threads (8 waves). i-space padded to 140 (slots 131..139 NEGV forever;
// pad candidates -2e4 provably lose). Waves 0..6 = sub (i-slice [sub*20, sub*20+20)):
// lane scans TWO columns (j = lane and j = 64+lane) from ONE shared slice read
// (5 wave-uniform ds_read_b128 -- broadcast, conflict-free; T = 2x20 = 40 floats,
// the size r11 proved register-resident at VGPR=48). Wave 7 = tail cols 128..130
// x 7 subs on lanes 0..20 (bank-disjoint slice reads). Combine: threads 0..130 max
// 7 partials (stride-1), blend, publish sbuf + hist. Two lgkm barriers/step.
// All ops exact fp32 add/fmax -> hist bit-identical to reference.
__global__ __launch_bounds__(512, 1) void viterbi_fwd(
    const float* __restrict__ feats, const float* __restrict__ mask,
    const float* __restrict__ trans, float* __restrict__ hist)
{
    const int b = blockIdx.x;
    const int tid = threadIdx.x;
    const int w = tid >> 6, lane = tid & 63;

    __shared__ float sbuf[2][144];     // [buf][i]; 131..143 = NEGV pad
    __shared__ float pbuf[7][132];     // [sub][col]

    const float* fb = feats + (size_t)b * LL * CP;
    const float* mb = mask + (size_t)b * LL;
    float* hb = hist + (size_t)b * LL * CP;

    // ---- per-wave scan setup ----
    int sub, trow = 0;
    bool twr = false;
    float4 TA[5], TB[5];               // TB used by main waves only
    if (w < 7) {
        sub = w;
        const int i0 = sub * 20;
        const float* trA = trans + (size_t)lane * CC;         // col lane
        const float* trB = trans + (size_t)(64 + lane) * CC;  // col 64+lane
#pragma unroll
        for (int q = 0; q < 5; ++q) {
            int i = i0 + 4 * q;
            TA[q].x = (i + 0 < CC) ? trA[i + 0] : NEGV;
            TA[q].y = (i + 1 < CC) ? trA[i + 1] : NEGV;
            TA[q].z = (i + 2 < CC) ? trA[i + 2] : NEGV;
            TA[q].w = (i + 3 < CC) ? trA[i + 3] : NEGV;
            TB[q].x = (i + 0 < CC) ? trB[i + 0] : NEGV;
            TB[q].y = (i + 1 < CC) ? trB[i + 1] : NEGV;
            TB[q].z = (i + 2 < CC) ? trB[i + 2] : NEGV;
            TB[q].w = (i + 3 < CC) ? trB[i + 3] : NEGV;
        }
    } else {
        const int ln = (lane < 21) ? lane : 20;
        const int s7 = ln / 3;
        const int r3 = ln - s7 * 3;
        sub = s7;                      // 0..6
        trow = 128 + r3;               // 128..130
        twr = (lane < 21);
        const int i0 = sub * 20;
        const float* tr = trans + (size_t)trow * CC;
#pragma unroll
        for (int q = 0; q < 5; ++q) {
            int i = i0 + 4 * q;
            TA[q].x = (i + 0 < CC) ? tr[i + 0] : NEGV;
            TA[q].y = (i + 1 < CC) ? tr[i + 1] : NEGV;
            TA[q].z = (i + 2 < CC) ? tr[i + 2] : NEGV;
            TA[q].w = (i + 3 < CC) ? tr[i + 3] : NEGV;
        }
    }

    // ---- init sbuf: all NEGV, [0][START]=0; pads 131..143 stay NEGV in both buffers
    for (int q = tid; q < 2 * 144; q += 512) {
        int bi = q / 144, idx = q - bi * 144;
        sbuf[bi][idx] = (bi == 0 && idx == START_I) ? 0.f : NEGV;
    }
    __syncthreads();

    // ---- combiner state (threads 0..130 own column k)
    const int k = tid;
    const bool cl = (tid < 131);
    float s_prev = (k == START_I) ? 0.f : NEGV;
    float fv0 = 0.f, fv1 = 0.f, mv0 = 1.f, mv1 = 1.f;
    if (cl) { fv0 = fb[k]; fv1 = fb[CP + k]; mv0 = mb[0]; mv1 = mb[1]; }
    const float* fb_t = fb + 2 * CP + k;
    const float* mb_t = mb + 2;
    float* hb_t = hb + k;

    for (int t = 0; t < LL; ++t) {
        const int rb = t & 1;

        // ================= phase A: scan s_t (all 8 waves) =================
        {
            const float4* s4 = (const float4*)(&sbuf[rb][0]) + sub * 5;
            if (w < 7) {
                float a0 = -3.0e38f, a1 = -3.0e38f, b0 = -3.0e38f, b1 = -3.0e38f;
#pragma unroll
                for (int q = 0; q < 5; ++q) {
                    float4 sv = s4[q];
                    a0 = fmaxf(fmaxf(sv.x + TA[q].x, sv.y + TA[q].y), a0);
                    a1 = fmaxf(fmaxf(sv.z + TA[q].z, sv.w + TA[q].w), a1);
                    b0 = fmaxf(fmaxf(sv.x + TB[q].x, sv.y + TB[q].y), b0);
                    b1 = fmaxf(fmaxf(sv.z + TB[q].z, sv.w + TB[q].w), b1);
                }
                pbuf[sub][lane] = fmaxf(a0, a1);
                pbuf[sub][64 + lane] = fmaxf(b0, b1);
            } else {
                float a0 = -3.0e38f, a1 = -3.0e38f;
#pragma unroll
                for (int q = 0; q < 5; ++q) {
                    float4 sv = s4[q];
                    a0 = fmaxf(fmaxf(sv.x + TA[q].x, sv.y + TA[q].y), a0);
                    a1 = fmaxf(fmaxf(sv.z + TA[q].z, sv.w + TA[q].w), a1);
                }
                if (twr) pbuf[sub][trow] = fmaxf(a0, a1);
            }
        }

        lds_barrier();   // pbuf published; sbuf[rb] reads complete

        // ================= phase B: combine (threads 0..130) =================
        float fv2 = 0.f, mv2 = 1.f;
        if (cl && t + 2 < LL) { fv2 = *fb_t; mv2 = *mb_t; }
        fb_t += CP; ++mb_t;

        if (cl) {
            float p = fmaxf(fmaxf(fmaxf(pbuf[0][k], pbuf[1][k]),
                                  fmaxf(pbuf[2][k], pbuf[3][k])),
                            fmaxf(fmaxf(pbuf[4][k], pbuf[5][k]), pbuf[6][k]));
            float ns = (mv0 != 0.f) ? (p + fv0) : s_prev;
            s_prev = ns;
            sbuf[rb ^ 1][k] = ns;
            *hb_t = ns;                 // global store; lds_barrier never drains it
        }
        hb_t += CP;

        lds_barrier();   // sbuf[rb^1] fully published

        fv0 = fv1; fv1 = fv2; mv0 = mv1; mv1 = mv2;
    }
}

// ---------------- Kernel 3: backpointer matrix (unchanged) ----------------
__global__ __launch_bounds__(256, 4) void bp_kernel(
    const float* __restrict__ hist, const float* __restrict__ trans,
    unsigned char* __restrict__ bp)
{
    const int b  = blockIdx.x / 5;
    const int jc = blockIdx.x % 5;
    const int tc = blockIdx.y;
    const int tid = threadIdx.x;
    const int j0 = jc * 32;

    __shared__ float Ts[32][136];
    __shared__ float hs[8][132];

    for (int q = 0; q < 17; ++q) {
        int lin = tid + q * 256;
        if (lin < 32 * CC) {
            int r = lin / CC, i = lin - r * CC;
            if (j0 + r < CC) Ts[r][i] = trans[(size_t)(j0 + r) * CC + i];
        }
    }
    {
        const float4* src = (const float4*)(hist + ((size_t)b * LL + tc * 8) * CP);
#pragma unroll
        for (int q = 0; q < 2; ++q) {
            int lin = tid + q * 256;
            if (lin < (8 * CP) / 4) ((float4*)hs)[lin] = src[lin];
        }
    }
    __syncthreads();

    const int jl = tid & 31;
    const int tt = tid >> 5;
    const int j = j0 + jl;
    const int t = tc * 8 + tt + 1;
    if (j >= CC || t >= LL) return;

    float best; int idx;
    {
        float4 tv = *(const float4*)&Ts[jl][128];
        float4 hv = *(const float4*)&hs[tt][128];
        best = hv.z + tv.z; idx = 130;
        float v;
        v = hv.y + tv.y; if (v >= best) { best = v; idx = 129; }
        v = hv.x + tv.x; if (v >= best) { best = v; idx = 128; }
    }
#pragma unroll
    for (int i4 = 31; i4 >= 0; --i4) {
        float4 tv = *(const float4*)&Ts[jl][i4 * 4];
        float4 hv = *(const float4*)&hs[tt][i4 * 4];
        float v;
        v = hv.w + tv.w; if (v >= best) { best = v; idx = i4 * 4 + 3; }
        v = hv.z + tv.z; if (v >= best) { best = v; idx = i4 * 4 + 2; }
        v = hv.y + tv.y; if (v >= best) { best = v; idx = i4 * 4 + 1; }
        v = hv.x + tv.x; if (v >= best) { best = v; idx = i4 * 4 + 0; }
    }
    bp[((size_t)b * LL + t) * CP + j] = (unsigned char)idx;
}

// ---------------- Kernel 4: final argmax + LDS-streamed u8 backtrack (unchanged) ------
__global__ __launch_bounds__(64, 1) void viterbi_btr(
    const float* __restrict__ hist, const float* __restrict__ trans,
    const unsigned char* __restrict__ bp,
    float* __restrict__ out_score, float* __restrict__ out_path)
{
    const int b = blockIdx.x;
    const int lane = threadIdx.x;
    const float* hb = hist + ((size_t)b * LL + (LL - 1)) * CP;
    const float* ts = trans + (size_t)STOP_I * CC;

    float v0 = hb[lane] + ts[lane];
    float v1 = hb[lane + 64] + ts[lane + 64];
    float v2 = (lane < 3) ? (hb[lane + 128] + ts[lane + 128]) : -3.0e38f;

    float best = v0; int idx = lane;
    if (v1 > best) { best = v1; idx = lane + 64; }
    if (v2 > best) { best = v2; idx = lane + 128; }
#pragma unroll
    for (int off = 32; off >= 1; off >>= 1) {
        float ob = __shfl_xor(best, off, 64);
        int   oi = __shfl_xor(idx, off, 64);
        if (ob > best || (ob == best && oi < idx)) { best = ob; idx = oi; }
    }

    float* op = out_path + (size_t)b * LL;
    if (lane == 0) {
        out_score[b] = best;
        op[LL - 1] = (float)idx;
    }
    int tag = idx;

    __shared__ unsigned char buf[2][1088];
    const unsigned char* bpb = bp + (size_t)b * LL * CP;

    {
        const unsigned int* src = (const unsigned int*)(bpb + (size_t)504 * CP);
        unsigned int* dst = (unsigned int*)buf[1];
#pragma unroll
        for (int q = 0; q < 5; ++q) {
            int lin = lane + q * 64;
            if (lin < 264) dst[lin] = src[lin];
        }
    }
    lds_barrier();

    int cur = 1;
    for (int k = 63; k >= 0; --k) {
        unsigned int r0 = 0, r1 = 0, r2 = 0, r3 = 0, r4 = 0;
        if (k > 0) {
            const unsigned int* src = (const unsigned int*)(bpb + (size_t)(k - 1) * 8 * CP);
            r0 = src[lane];
            r1 = src[lane + 64];
            r2 = src[lane + 128];
            r3 = src[lane + 192];
            if (lane < 8) r4 = src[lane + 256];
        }
        const unsigned char* cb = buf[cur];
#pragma unroll
        for (int s = 7; s >= 0; --s) {
            int t = k * 8 + s;
            if (t >= 1) {
                tag = cb[s * CP + tag];
                if (lane == 0) op[t - 1] = (float)tag;
            }
        }
        if (k > 0) {
            unsigned int* dst = (unsigned int*)buf[cur ^ 1];
            dst[lane] = r0;
            dst[lane + 64] = r1;
            dst[lane + 128] = r2;
            dst[lane + 192] = r3;
            if (lane < 8) dst[lane + 256] = r4;
            lds_barrier();
        }
        cur ^= 1;
    }
}

extern "C" void kernel_launch(void* const* d_in, const int* in_sizes, int n_in,
                              void* d_out, int out_size, void* d_ws, size_t ws_size,
                              hipStream_t stream)
{
    const float* x     = (const float*)d_in[0];
    const float* mask  = (const float*)d_in[1];
    const float* W     = (const float*)d_in[2];
    const float* bias  = (const float*)d_in[3];
    const float* trans = (const float*)d_in[4];

    float* feats = (float*)d_ws;
    float* hist  = feats + (size_t)BB * LL * CP;
    unsigned char* bp = (unsigned char*)(hist + (size_t)BB * LL * CP);
    float* out_score = (float*)d_out;
    float* out_path  = out_score + BB;

    hipLaunchKernelGGL(gemm_feats, dim3((BB * LL) / GM), dim3(256), 0, stream, x, W, bias, feats);
    hipLaunchKernelGGL(viterbi_fwd, dim3(BB), dim3(512), 0, stream, feats, mask, trans, hist);
    hipLaunchKernelGGL(bp_kernel, dim3(BB * 5, 64), dim3(256), 0, stream, hist, trans, bp);
    hipLaunchKernelGGL(viterbi_btr, dim3(BB), dim3(64), 0, stream, hist, trans, bp, out_score, out_path);
}